// Round 2
// baseline (271.446 us; speedup 1.0000x reference)
//
#include <hip/hip_runtime.h>

#define N_NODES 1024
#define C_CH    128
#define L_ELL   16
#define N_ELEM  10
#define K3      11
#define K2      4

// 64 FMAs: a_j += t3q[j][q] . xq_q  (all indices compile-time)
#define FMA4(J, Q, XV)                                  \
  a##J = fmaf(t3q[J][Q].x, XV.x, a##J);                 \
  a##J = fmaf(t3q[J][Q].y, XV.y, a##J);                 \
  a##J = fmaf(t3q[J][Q].z, XV.z, a##J);                 \
  a##J = fmaf(t3q[J][Q].w, XV.w, a##J);

__global__ __launch_bounds__(256, 4) void sym_contract_kernel(
    const float* __restrict__ node_feats,   // [N, C, 16]
    const float* __restrict__ node_attrs,   // [N, 10]
    const float* __restrict__ U03, const float* __restrict__ W03,
    const float* __restrict__ U02, const float* __restrict__ W02,
    const float* __restrict__ U01, const float* __restrict__ W01,
    const float* __restrict__ U13, const float* __restrict__ W13,
    const float* __restrict__ U12, const float* __restrict__ W12,
    const float* __restrict__ U11, const float* __restrict__ W11,
    float* __restrict__ feats_out)          // [N, C*4] pre-linear (= d_out)
{
  __shared__ float T3s[4096];               // one m-slice, XOR-swizzled
  __shared__ unsigned short nodelist[N_NODES];
  __shared__ float wrow[32];
  __shared__ int cnt;

  const int e    = blockIdx.x / C_CH;
  const int c    = blockIdx.x % C_CH;
  const int tid  = threadIdx.x;
  const int m    = tid >> 6;                // wave id = output slot
  const int lane = tid & 63;
  const int g    = lane >> 4;               // i2-quad
  const int i1   = lane & 15;

  if (tid == 0) cnt = 0;
  if (tid < 32) {
    float v;
    if (tid < 11)       v = W03[(e * K3 + tid) * C_CH + c];
    else if (tid < 15)  v = W02[(e * K2 + (tid - 11)) * C_CH + c];
    else if (tid == 15) v = W01[e * C_CH + c];
    else if (tid < 27)  v = W13[(e * K3 + (tid - 16)) * C_CH + c];
    else if (tid < 31)  v = W12[(e * K2 + (tid - 27)) * C_CH + c];
    else                v = W11[e * C_CH + c];
    wrow[tid] = v;
  }
  __syncthreads();

  // node list for this element
  for (int b = tid; b < N_NODES; b += 256)
    if (node_attrs[b * N_ELEM + e] > 0.5f) {
      int p = atomicAdd(&cnt, 1);
      nodelist[p] = (unsigned short)b;
    }

  // --- T2, T1 straight into registers ---
  float t2[4];
  {
    const int wb = (m == 0) ? 11 : 27;
    float w2v[4];
    #pragma unroll
    for (int k = 0; k < 4; ++k) w2v[k] = wrow[wb + k];
    #pragma unroll
    for (int j = 0; j < 4; ++j) {
      const int r2 = i1 * 16 + 4 * g + j;
      const float4 u2 = (m == 0)
          ? *(const float4*)(U02 + r2 * K2)
          : *(const float4*)(U12 + ((m - 1) * 256 + r2) * K2);
      t2[j] = u2.x * w2v[0] + u2.y * w2v[1] + u2.z * w2v[2] + u2.w * w2v[3];
    }
  }
  const float t1 = (m == 0) ? U01[i1] * wrow[15]
                            : U11[(m - 1) * 16 + i1] * wrow[31];

  // --- T3 into registers: build one m-slice at a time in LDS ---
  float4 t3q[4][4];                          // [j = i2 sub][q = i3 quad]
  const int xorv = (i1 & 7) << 2;
  for (int s = 0; s < 4; ++s) {
    __syncthreads();                         // previous slice fully consumed
    const int wb = (s == 0) ? 0 : 16;
    float wk[K3];
    #pragma unroll
    for (int k = 0; k < K3; ++k) wk[k] = wrow[wb + k];
    const float* U3 = (s == 0) ? U03 : (U13 + (size_t)(s - 1) * 4096 * K3);
    for (int w = tid; w < 4096; w += 256) {
      const float* up = U3 + (size_t)w * K3;
      float acc = 0.f;
      #pragma unroll
      for (int k = 0; k < K3; ++k) acc = fmaf(up[k], wk[k], acc);
      T3s[w ^ (((w >> 8) & 7) << 2)] = acc;
    }
    __syncthreads();
    if (m == s) {
      #pragma unroll
      for (int j = 0; j < 4; ++j)
        #pragma unroll
        for (int q = 0; q < 4; ++q) {
          const int el = i1 * 256 + (4 * g + j) * 16 + q * 4;
          t3q[j][q] = *(const float4*)&T3s[el ^ xorv];
        }
    }
  }
  __syncthreads();

  // --- phase B: loop nodes, all operands register/L1-resident ---
  const int total = cnt;
  for (int n = 0; n < total; ++n) {
    const int b = nodelist[n];
    const float* xr = node_feats + ((size_t)b * C_CH + c) * L_ELL;
    const float4 xq0 = ((const float4*)xr)[0];   // wave-uniform addr -> L1 broadcast
    const float4 xq1 = ((const float4*)xr)[1];
    const float4 xq2 = ((const float4*)xr)[2];
    const float4 xq3 = ((const float4*)xr)[3];
    const float4 xg  = ((const float4*)xr)[g];   // lane-dep, one 64B line
    const float  xi  = xr[i1];

    float a0 = t2[0], a1 = t2[1], a2 = t2[2], a3 = t2[3];
    FMA4(0, 0, xq0) FMA4(0, 1, xq1) FMA4(0, 2, xq2) FMA4(0, 3, xq3)
    FMA4(1, 0, xq0) FMA4(1, 1, xq1) FMA4(1, 2, xq2) FMA4(1, 3, xq3)
    FMA4(2, 0, xq0) FMA4(2, 1, xq1) FMA4(2, 2, xq2) FMA4(2, 3, xq3)
    FMA4(3, 0, xq0) FMA4(3, 1, xq1) FMA4(3, 2, xq2) FMA4(3, 3, xq3)

    float p = a0 * xg.x + a1 * xg.y + a2 * xg.z + a3 * xg.w;
    p += __shfl_xor(p, 16);
    p += __shfl_xor(p, 32);                  // sum over i2-quads g
    float r = (p + t1) * xi;
    r += __shfl_xor(r, 1);
    r += __shfl_xor(r, 2);
    r += __shfl_xor(r, 4);
    r += __shfl_xor(r, 8);                   // sum over i1
    if (lane == 0)
      feats_out[(size_t)b * 512 + c * 4 + m] = r;
  }
}

__global__ __launch_bounds__(256) void linear_kernel(
    const float* __restrict__ sc,
    const float* __restrict__ lin0,
    const float* __restrict__ lin1,
    float* __restrict__ io)             // d_out, in-place per-row
{
  __shared__ float f[512];              // [c][m]
  const int b   = blockIdx.x;
  const int tid = threadIdx.x;
  const float* row = io + (size_t)b * 512;
  if (tid < 128) ((float4*)f)[tid] = ((const float4*)row)[tid];
  __syncthreads();
  const float inv_sqrt_c = 0.088388347648318447f;   // 1/sqrt(128)
  #pragma unroll
  for (int rep = 0; rep < 2; ++rep) {
    const int o = tid + rep * 256;
    float acc = 0.f;
    if (o < 128) {
      const int fo = o;
      #pragma unroll 4
      for (int ci = 0; ci < 128; ++ci) acc += f[ci * 4] * lin0[ci * 128 + fo];
    } else {
      const int oo = o - 128;
      const int fo = oo / 3;
      const int dd = oo - fo * 3;
      #pragma unroll 4
      for (int ci = 0; ci < 128; ++ci) acc += f[ci * 4 + 1 + dd] * lin1[ci * 128 + fo];
    }
    io[(size_t)b * 512 + o] = acc * inv_sqrt_c + sc[(size_t)b * 512 + o];
  }
}

extern "C" void kernel_launch(void* const* d_in, const int* in_sizes, int n_in,
                              void* d_out, int out_size, void* d_ws, size_t ws_size,
                              hipStream_t stream) {
  const float* node_feats = (const float*)d_in[0];
  const float* sc         = (const float*)d_in[1];
  const float* node_attrs = (const float*)d_in[2];
  const float* U01  = (const float*)d_in[3];
  const float* W01  = (const float*)d_in[4];
  const float* U02  = (const float*)d_in[5];
  const float* W02  = (const float*)d_in[6];
  const float* U03  = (const float*)d_in[7];
  const float* W03  = (const float*)d_in[8];
  const float* lin0 = (const float*)d_in[9];
  const float* U11  = (const float*)d_in[10];
  const float* W11  = (const float*)d_in[11];
  const float* U12  = (const float*)d_in[12];
  const float* W12  = (const float*)d_in[13];
  const float* U13  = (const float*)d_in[14];
  const float* W13  = (const float*)d_in[15];
  const float* lin1 = (const float*)d_in[16];
  float* out = (float*)d_out;

  sym_contract_kernel<<<N_ELEM * C_CH, 256, 0, stream>>>(
      node_feats, node_attrs,
      U03, W03, U02, W02, U01, W01,
      U13, W13, U12, W12, U11, W11, out);
  linear_kernel<<<N_NODES, 256, 0, stream>>>(sc, lin0, lin1, out);
}